// Round 18
// baseline (243.824 us; speedup 1.0000x reference)
//
#include <hip/hip_runtime.h>
#include <hip/hip_bf16.h>
#include <cmath>

typedef __bf16 bf16;
typedef __bf16 bf16x8 __attribute__((ext_vector_type(8)));
typedef __bf16 bf16x4 __attribute__((ext_vector_type(4)));
typedef __bf16 bf16x2 __attribute__((ext_vector_type(2)));
typedef float  f32x4  __attribute__((ext_vector_type(4)));
typedef float  f32x16 __attribute__((ext_vector_type(16)));
typedef int    i32x4  __attribute__((ext_vector_type(4)));

#define B_   2
#define T_   2048
#define D_   1024
#define H_   16
#define DH_  64
#define BT_  (B_ * T_)     // 4096
#define DFF_ (4 * D_)      // 4096

#define GLDS(gp, lp) __builtin_amdgcn_global_load_lds( \
    (const __attribute__((address_space(1))) void*)(gp), \
    (__attribute__((address_space(3))) void*)(lp), 16, 0, 0)
#define VMCNT(n) asm volatile("s_waitcnt vmcnt(" #n ")" ::: "memory")

// ---------------- fused fp32 -> bf16 convert for ALL weights/activations ----------
__global__ __launch_bounds__(256) void cvt_all(
    const float* __restrict__ x,  const float* __restrict__ wq,
    const float* __restrict__ wk, const float* __restrict__ wv,
    const float* __restrict__ w1, const float* __restrict__ w2,
    bf16* __restrict__ xb, bf16* __restrict__ wall,
    bf16* __restrict__ w1b, bf16* __restrict__ w2b)
{
    const int blk = blockIdx.x;
    const float* src; bf16* dst; int off;
    if      (blk < 4096)  { src = x;  dst = xb;                 off = blk;         }
    else if (blk < 5120)  { src = wq; dst = wall;               off = blk - 4096;  }
    else if (blk < 6144)  { src = wk; dst = wall + (1 << 20);   off = blk - 5120;  }
    else if (blk < 7168)  { src = wv; dst = wall + (2 << 20);   off = blk - 6144;  }
    else if (blk < 11264) { src = w1; dst = w1b;                off = blk - 7168;  }
    else                  { src = w2; dst = w2b;                off = blk - 11264; }
    const long i = (long)off * 1024 + threadIdx.x * 4;
    float4 v = *(const float4*)(src + i);
    bf16x4 o;
    o[0] = (bf16)v.x; o[1] = (bf16)v.y; o[2] = (bf16)v.z; o[3] = (bf16)v.w;
    *(bf16x4*)(dst + i) = o;
}

// tanh-form GELU (one __expf; |err| vs exact ~1e-3, within budget)
__device__ __forceinline__ float gelu_f(float v) {
    float u = v * (0.7978845608f + 0.0356774081f * v * v);
    return v / (1.f + __expf(-2.f * u));
}

__device__ __forceinline__ int pkbf(float a, float b) {
    bf16x2 v; v[0] = (bf16)a; v[1] = (bf16)b;
    return __builtin_bit_cast(int, v);
}

// ---------------- V transpose: vrow [B][T][1024] -> vt [B][1024][T] ----------------
__global__ __launch_bounds__(256) void transpose_v(
    const bf16* __restrict__ vrow, bf16* __restrict__ vt)
{
    __shared__ bf16 tile[64][72];
    const int tb = blockIdx.x;
    const int eb = blockIdx.y;
    const int b  = blockIdx.z;
    const int c  = threadIdx.x;

    const bf16* src = vrow + ((long)b * T_ + tb * 64) * 1024 + eb * 64;
    #pragma unroll
    for (int j = 0; j < 2; j++) {
        int ch = c + j * 256;
        int r = ch >> 3, s = ch & 7;
        *(bf16x8*)&tile[r][s * 8] = *(const bf16x8*)&src[(long)r * 1024 + s * 8];
    }
    __syncthreads();
    bf16* dst = vt + ((long)b * 1024 + eb * 64) * 2048 + tb * 64;
    #pragma unroll
    for (int j = 0; j < 2; j++) {
        int ch = c + j * 256;
        int r = ch >> 3, s = ch & 7;
        bf16x8 o;
        #pragma unroll
        for (int k = 0; k < 8; k++) o[k] = tile[s * 8 + k][r];
        *(bf16x8*)&dst[(long)r * 2048 + s * 8] = o;
    }
}

// ---------------- GEMM: C[M,N] = A[M,K] * Bt[N,K]^T  (round-9 proven structure) ---
// 128x128 tile, ring-2 LDS double-buffer, stage-early, single vmcnt(0)+barrier
// per K-step. BKT=64: halves per-step sync events; both-sides seg^=(row&7)
// XOR swizzle (linear gload_lds dest + pre-swizzled source + XOR'd ds_read).
// EPI 1: bf16 out = gelu(acc + bias)
// EPI 2 (SK): split-K over blockIdx.z; f32 atomicAdd into pre-zeroed out;
//   z==0 contributes bias+resid. XCD-region remap on the 8x32 (x,y) grid.
// EPI 3: QKV split: col < 2048 -> qk [M][2048]; col >= 2048 -> vrow [M][1024]
template <int EPI, int SK = 1, int BKT = 32>
__global__ __launch_bounds__(256) void gemm_bt(
    const bf16* __restrict__ A, const bf16* __restrict__ Bt,
    void* __restrict__ outp, void* __restrict__ outp2, const float* __restrict__ bias,
    const float* __restrict__ resid, int M, int N, int K)
{
    __shared__ __align__(16) bf16 As[2][128 * BKT];
    __shared__ __align__(16) bf16 Bs[2][128 * BKT];
    const int tid  = threadIdx.x;
    const int lane = tid & 63;
    const int w    = tid >> 6;
    const int wr   = w >> 1, wc = w & 1;
    const int g    = lane >> 4, cc = lane & 15;

    int bx = blockIdx.x, by = blockIdx.y;
    if constexpr (EPI == 2) {
        const int L = blockIdx.y * 8 + blockIdx.x;
        const int xcd = L & 7, grp = L >> 3;
        by = xcd * 4 + (grp >> 3);
        bx = grp & 7;
    }
    const int m0 = by * 128, n0 = bx * 128;
    const int NT = (K / SK) / BKT;
    const long koff = (long)blockIdx.z * (K / SK);

    f32x4 acc[4][4] = {};

    const int c0 = tid, c1 = tid + 256;
    const bf16* gA0 = A  + (long)(m0 + (c0 >> 2)) * K + koff + ((c0 & 3) << 3);
    const bf16* gA1 = A  + (long)(m0 + (c1 >> 2)) * K + koff + ((c1 & 3) << 3);
    const bf16* gB0 = Bt + (long)(n0 + (c0 >> 2)) * K + koff + ((c0 & 3) << 3);
    const bf16* gB1 = Bt + (long)(n0 + (c1 >> 2)) * K + koff + ((c1 & 3) << 3);

    auto stage = [&](int t) {
        const int buf = t & 1;
        if constexpr (BKT == 32) {
            const long k0 = (long)t << 5;
            GLDS(gA0 + k0, &As[buf][c0 * 8]);
            GLDS(gA1 + k0, &As[buf][c1 * 8]);
            GLDS(gB0 + k0, &Bs[buf][c0 * 8]);
            GLDS(gB1 + k0, &Bs[buf][c1 * 8]);
        } else {
            const long k0 = koff + (long)t * BKT;
            #pragma unroll
            for (int j = 0; j < 4; j++) {
                int c = tid + j * 256;
                int r = c >> 3;
                int s = ((c & 7) ^ (r & 7)) << 3;
                GLDS(A  + (long)(m0 + r) * K + k0 + s, &As[buf][c * 8]);
                GLDS(Bt + (long)(n0 + r) * K + k0 + s, &Bs[buf][c * 8]);
            }
        }
    };

    stage(0);
    VMCNT(0);
    __builtin_amdgcn_s_barrier();

    for (int t = 0; t < NT; ++t) {
        const bf16* Ab = As[t & 1];
        const bf16* Bb = Bs[t & 1];
        if (t + 1 < NT) stage(t + 1);

        if constexpr (BKT == 32) {
            bf16x8 af[4], bfr[4];
            #pragma unroll
            for (int mi = 0; mi < 4; mi++)
                af[mi] = *(const bf16x8*)&Ab[(wr * 64 + mi * 16 + cc) * 32 + g * 8];
            #pragma unroll
            for (int ni = 0; ni < 4; ni++)
                bfr[ni] = *(const bf16x8*)&Bb[(wc * 64 + ni * 16 + cc) * 32 + g * 8];
            #pragma unroll
            for (int mi = 0; mi < 4; mi++)
                #pragma unroll
                for (int ni = 0; ni < 4; ni++)
                    acc[mi][ni] = __builtin_amdgcn_mfma_f32_16x16x32_bf16(af[mi], bfr[ni], acc[mi][ni], 0, 0, 0);
        } else {
            const int key = cc & 7;
            bf16x8 af[4][2], bfr[4][2];
            #pragma unroll
            for (int mi = 0; mi < 4; mi++)
                #pragma unroll
                for (int kt = 0; kt < 2; kt++) {
                    int row = wr * 64 + mi * 16 + cc;
                    int sl  = ((kt << 2) | g) ^ key;
                    af[mi][kt] = *(const bf16x8*)&Ab[row * 64 + sl * 8];
                }
            #pragma unroll
            for (int ni = 0; ni < 4; ni++)
                #pragma unroll
                for (int kt = 0; kt < 2; kt++) {
                    int row = wc * 64 + ni * 16 + cc;
                    int sl  = ((kt << 2) | g) ^ key;
                    bfr[ni][kt] = *(const bf16x8*)&Bb[row * 64 + sl * 8];
                }
            #pragma unroll
            for (int kt = 0; kt < 2; kt++)
                #pragma unroll
                for (int mi = 0; mi < 4; mi++)
                    #pragma unroll
                    for (int ni = 0; ni < 4; ni++)
                        acc[mi][ni] = __builtin_amdgcn_mfma_f32_16x16x32_bf16(
                            af[mi][kt], bfr[ni][kt], acc[mi][ni], 0, 0, 0);
        }

        VMCNT(0);
        __builtin_amdgcn_s_barrier();
    }

    #pragma unroll
    for (int mi = 0; mi < 4; mi++) {
        #pragma unroll
        for (int ni = 0; ni < 4; ni++) {
            #pragma unroll
            for (int r = 0; r < 4; r++) {
                int grow = m0 + wr * 64 + mi * 16 + g * 4 + r;
                int gcol = n0 + wc * 64 + ni * 16 + cc;
                float v = acc[mi][ni][r];
                if constexpr (EPI == 3) {
                    if (gcol < 2048)
                        ((bf16*)outp)[(long)grow * 2048 + gcol] = (bf16)v;
                    else
                        ((bf16*)outp2)[(long)grow * 1024 + (gcol - 2048)] = (bf16)v;
                } else if constexpr (EPI == 1) {
                    v += bias[gcol];
                    ((bf16*)outp)[(long)grow * N + gcol] = (bf16)gelu_f(v);
                } else {
                    if (blockIdx.z == 0)
                        v += bias[gcol] + resid[(long)grow * N + gcol];
                    atomicAdd(&((float*)outp)[(long)grow * N + gcol], v);
                }
            }
        }
    }
}

// ---------------- flash attention v6: swapped-QK 32x32 MFMA, exp2-domain softmax ---
// log2(e) folded into Q scale -> S is log2-domain; exp2f = bare v_exp_f32
// (saves the per-element *1.4427 mul on the serial softmax chain).
// Complementary qt pairing: co-resident blocks (same x,y; b=0/1) get qt = 15-x and x.
__global__ __launch_bounds__(256) void attn_kernel(
    const bf16* __restrict__ qk, const bf16* __restrict__ vt,
    const float* __restrict__ x, bf16* __restrict__ hout)
{
    __shared__ __align__(16) bf16 Ks[2][64 * 64];
    __shared__ __align__(16) bf16 Vs[2][64 * 64];
    const int tid  = threadIdx.x;
    const int lane = tid & 63, w = tid >> 6;
    const int l31 = lane & 31, hi = lane >> 5;
    const int b = blockIdx.z;
    const int qb = b ? blockIdx.x : (gridDim.x - 1 - blockIdx.x);
    const int hh = blockIdx.y;
    const int qbase = qb * 128;
    const int qw0 = qbase + w * 32;
    const int qg  = qw0 + l31;

    const bf16* qkb   = qk + (long)b * T_ * 2048;
    const bf16* kbase = qkb + 1024 + hh * 64;
    const bf16* vbase = vt + ((long)b * 1024 + hh * 64) * 2048;

    // Q scale = 1/8 * log2(e): S comes out of QK^T already in log2 units
    bf16x8 qf[4];
    {
        const bf16* qrow = qkb + (long)qg * 2048 + hh * 64;
        #pragma unroll
        for (int ks = 0; ks < 4; ks++) {
            bf16x8 v = *(const bf16x8*)&qrow[ks * 16 + hi * 8];
            #pragma unroll
            for (int j = 0; j < 8; j++) v[j] = (bf16)((float)v[j] * 0.18033688f);
            qf[ks] = v;
        }
    }

    float m_run = -INFINITY, l_run = 0.f;
    f32x16 o0 = {}, o1 = {};

    const int ntiles = (qbase >> 6) + 2;
    const int my_end = ((qw0 + 31) >> 6) + 1;

    auto stage = [&](int i) {
        const int buf = i & 1;
        const long kv0 = (long)i << 6;
        #pragma unroll
        for (int j = 0; j < 2; j++) {
            int c = tid + j * 256;
            int r = c >> 3, s = c & 7;
            int seg = (s ^ (r & 7)) << 3;
            GLDS(kbase + (kv0 + r) * 2048 + seg, &Ks[buf][c * 8]);
            GLDS(vbase + (long)r * 2048 + kv0 + seg, &Vs[buf][c * 8]);
        }
    };

    stage(0);
    __syncthreads();

    for (int i = 0; i < ntiles; ++i) {
        const int buf = i & 1;
        const int kv0 = i << 6;
        if (i + 1 < ntiles) stage(i + 1);

        if (i < my_end) {
            f32x16 s0 = {}, s1 = {};
            const int xk = l31 & 7;
            #pragma unroll
            for (int ks = 0; ks < 4; ks++) {
                int slot = ((2 * ks + hi) ^ xk) << 3;
                bf16x8 kf0 = *(const bf16x8*)&Ks[buf][l31 * 64 + slot];
                bf16x8 kf1 = *(const bf16x8*)&Ks[buf][(32 + l31) * 64 + slot];
                s0 = __builtin_amdgcn_mfma_f32_32x32x16_bf16(kf0, qf[ks], s0, 0, 0, 0);
                s1 = __builtin_amdgcn_mfma_f32_32x32x16_bf16(kf1, qf[ks], s1, 0, 0, 0);
            }

            if (kv0 + 64 > qw0) {
                #pragma unroll
                for (int r = 0; r < 16; r++) {
                    int kvr = kv0 + (r & 3) + 8 * (r >> 2) + 4 * hi;
                    if (kvr > qg)      s0[r] = -INFINITY;
                    if (kvr + 32 > qg) s1[r] = -INFINITY;
                }
            }

            float pm = s0[0];
            #pragma unroll
            for (int r = 1; r < 16; r++) pm = fmaxf(pm, s0[r]);
            #pragma unroll
            for (int r = 0; r < 16; r++) pm = fmaxf(pm, s1[r]);
            pm = fmaxf(pm, __shfl_xor(pm, 32));

            // defer-max: threshold 8 nats = 11.5416 log2-units
            if (!__all(pm <= m_run + 11.5416f)) {
                float mn = fmaxf(m_run, pm);
                float al = exp2f(m_run - mn);
                m_run = mn;
                l_run *= al;
                #pragma unroll
                for (int r = 0; r < 16; r++) {
                    float av = __shfl(al, (r & 3) + 8 * (r >> 2) + 4 * hi);
                    o0[r] *= av; o1[r] *= av;
                }
            }

            float rs = 0.f;
            #pragma unroll
            for (int r = 0; r < 16; r++) { float p = exp2f(s0[r] - m_run); s0[r] = p; rs += p; }
            #pragma unroll
            for (int r = 0; r < 16; r++) { float p = exp2f(s1[r] - m_run); s1[r] = p; rs += p; }
            rs += __shfl_xor(rs, 32);
            l_run += rs;

            i32x4 pw[4];
            {
                int d0[4], d1[4];
                #pragma unroll
                for (int m = 0; m < 4; m++) {
                    d0[m] = pkbf(s0[4 * m],     s0[4 * m + 1]);
                    d1[m] = pkbf(s0[4 * m + 2], s0[4 * m + 3]);
                }
                #pragma unroll
                for (int k2 = 0; k2 < 2; k2++) {
                    int r0 = __shfl_xor(d0[2 * k2 + 1 - hi], 32);
                    int r1 = __shfl_xor(d1[2 * k2 + 1 - hi], 32);
                    i32x4 t;
                    t[0] = hi ? r0 : d0[2 * k2];
                    t[1] = hi ? r1 : d1[2 * k2];
                    t[2] = hi ? d0[2 * k2 + 1] : r0;
                    t[3] = hi ? d1[2 * k2 + 1] : r1;
                    pw[k2] = t;
                }
            }
            {
                int d0[4], d1[4];
                #pragma unroll
                for (int m = 0; m < 4; m++) {
                    d0[m] = pkbf(s1[4 * m],     s1[4 * m + 1]);
                    d1[m] = pkbf(s1[4 * m + 2], s1[4 * m + 3]);
                }
                #pragma unroll
                for (int k2 = 0; k2 < 2; k2++) {
                    int r0 = __shfl_xor(d0[2 * k2 + 1 - hi], 32);
                    int r1 = __shfl_xor(d1[2 * k2 + 1 - hi], 32);
                    i32x4 t;
                    t[0] = hi ? r0 : d0[2 * k2];
                    t[1] = hi ? r1 : d1[2 * k2];
                    t[2] = hi ? d0[2 * k2 + 1] : r0;
                    t[3] = hi ? d1[2 * k2 + 1] : r1;
                    pw[2 + k2] = t;
                }
            }

            #pragma unroll
            for (int sl = 0; sl < 4; sl++) {
                bf16x8 pa = __builtin_bit_cast(bf16x8, pw[sl]);
                int slot = ((2 * sl + hi) ^ xk) << 3;
                bf16x8 vf0 = *(const bf16x8*)&Vs[buf][l31 * 64 + slot];
                bf16x8 vf1 = *(const bf16x8*)&Vs[buf][(32 + l31) * 64 + slot];
                o0 = __builtin_amdgcn_mfma_f32_32x32x16_bf16(pa, vf0, o0, 0, 0, 0);
                o1 = __builtin_amdgcn_mfma_f32_32x32x16_bf16(pa, vf1, o1, 0, 0, 0);
            }
        }
        __syncthreads();
    }

    #pragma unroll
    for (int r = 0; r < 16; r++) {
        int qr = (r & 3) + 8 * (r >> 2) + 4 * hi;
        float lr = __shfl(l_run, qr);
        float inv = __builtin_amdgcn_rcpf(lr);   // 1 ulp rcp; budget ok
        int grow = qbase + w * 32 + qr;
        long base = ((long)b * T_ + grow) * 1024 + hh * 64 + l31;
        hout[base]      = (bf16)(x[base]      + o0[r] * inv);
        hout[base + 32] = (bf16)(x[base + 32] + o1[r] * inv);
    }
}

// ---------------- launch ----------------
extern "C" void kernel_launch(void* const* d_in, const int* in_sizes, int n_in,
                              void* d_out, int out_size, void* d_ws, size_t ws_size,
                              hipStream_t stream) {
    const float* x  = (const float*)d_in[0];
    const float* wq = (const float*)d_in[2];
    const float* wk = (const float*)d_in[3];
    const float* wv = (const float*)d_in[4];
    const float* w1 = (const float*)d_in[5];
    const float* b1 = (const float*)d_in[6];
    const float* w2 = (const float*)d_in[7];
    const float* b2 = (const float*)d_in[8];
    float* out = (float*)d_out;

    char* ws = (char*)d_ws;
    bf16* xb   = (bf16*)(ws);                  // [4096,1024]   8 MB
    bf16* wall = (bf16*)(ws + (8L  << 20));    // [3072,1024]   6 MB
    bf16* w1b  = (bf16*)(ws + (14L << 20));    // [4096,1024]   8 MB
    bf16* w2b  = (bf16*)(ws + (22L << 20));    // [1024,4096]   8 MB
    bf16* qkb  = (bf16*)(ws + (30L << 20));    // [4096,2048]  16 MB
    bf16* vtb  = (bf16*)(ws + (46L << 20));    // [2,1024,2048] 8 MB
    bf16* hbuf = (bf16*)(ws + (54L << 20));    // [4096,1024]   8 MB (also vrow scratch)
    bf16* abuf = (bf16*)(ws + (62L << 20));    // [4096,4096]  32 MB
    bf16* vrow = hbuf;  // consumed by transpose_v BEFORE attn writes hbuf

    // zero out for split-K atomic accumulation (re-zeroed every replay)
    hipMemsetAsync(out, 0, (size_t)BT_ * D_ * sizeof(float), stream);

    // one fused convert dispatch: 15M elems -> 15360 blocks
    cvt_all<<<15360, 256, 0, stream>>>(x, wq, wk, wv, w1, w2, xb, wall, w1b, w2b);

    // QKV projection (BK=64): -> qk [4096,2048] + vrow [4096,1024]
    gemm_bt<3, 1, 64><<<dim3(3 * D_ / 128, BT_ / 128), 256, 0, stream>>>(
        xb, wall, qkb, vrow, nullptr, nullptr, BT_, 3 * D_, D_);

    // V transpose: vrow -> vt [2][1024][2048]
    transpose_v<<<dim3(T_ / 64, D_ / 64, B_), 256, 0, stream>>>(vrow, vtb);

    // attention + residual: hbuf = x + attn_out  (complementary qt pairing)
    attn_kernel<<<dim3(T_ / 128, H_, B_), 256, 0, stream>>>(qkb, vtb, x, hbuf);

    // FFN1 (BK=64): gelu(h @ w1^T + b1) -> abuf [4096,4096] bf16
    gemm_bt<1, 1, 64><<<dim3(DFF_ / 128, BT_ / 128), 256, 0, stream>>>(
        hbuf, w1b, abuf, nullptr, b1, nullptr, BT_, DFF_, D_);

    // FFN2 split-K=2, BK=64 + bias + residual x -> out fp32 [4096,1024] (atomic f32)
    gemm_bt<2, 2, 64><<<dim3(D_ / 128, BT_ / 128, 2), 256, 0, stream>>>(
        abuf, w2b, out, nullptr, b2, x, BT_, D_, DFF_);
}

// Round 19
// 236.256 us; speedup vs baseline: 1.0320x; 1.0320x over previous
//
#include <hip/hip_runtime.h>
#include <hip/hip_bf16.h>
#include <cmath>

typedef __bf16 bf16;
typedef __bf16 bf16x8 __attribute__((ext_vector_type(8)));
typedef __bf16 bf16x4 __attribute__((ext_vector_type(4)));
typedef __bf16 bf16x2 __attribute__((ext_vector_type(2)));
typedef float  f32x4  __attribute__((ext_vector_type(4)));
typedef float  f32x16 __attribute__((ext_vector_type(16)));
typedef int    i32x4  __attribute__((ext_vector_type(4)));

#define B_   2
#define T_   2048
#define D_   1024
#define H_   16
#define DH_  64
#define BT_  (B_ * T_)     // 4096
#define DFF_ (4 * D_)      // 4096

#define GLDS(gp, lp) __builtin_amdgcn_global_load_lds( \
    (const __attribute__((address_space(1))) void*)(gp), \
    (__attribute__((address_space(3))) void*)(lp), 16, 0, 0)
#define VMCNT(n) asm volatile("s_waitcnt vmcnt(" #n ")" ::: "memory")

// ---------------- fused fp32 -> bf16 convert for ALL weights/activations ----------
__global__ __launch_bounds__(256) void cvt_all(
    const float* __restrict__ x,  const float* __restrict__ wq,
    const float* __restrict__ wk, const float* __restrict__ wv,
    const float* __restrict__ w1, const float* __restrict__ w2,
    bf16* __restrict__ xb, bf16* __restrict__ wall,
    bf16* __restrict__ w1b, bf16* __restrict__ w2b)
{
    const int blk = blockIdx.x;
    const float* src; bf16* dst; int off;
    if      (blk < 4096)  { src = x;  dst = xb;                 off = blk;         }
    else if (blk < 5120)  { src = wq; dst = wall;               off = blk - 4096;  }
    else if (blk < 6144)  { src = wk; dst = wall + (1 << 20);   off = blk - 5120;  }
    else if (blk < 7168)  { src = wv; dst = wall + (2 << 20);   off = blk - 6144;  }
    else if (blk < 11264) { src = w1; dst = w1b;                off = blk - 7168;  }
    else                  { src = w2; dst = w2b;                off = blk - 11264; }
    const long i = (long)off * 1024 + threadIdx.x * 4;
    float4 v = *(const float4*)(src + i);
    bf16x4 o;
    o[0] = (bf16)v.x; o[1] = (bf16)v.y; o[2] = (bf16)v.z; o[3] = (bf16)v.w;
    *(bf16x4*)(dst + i) = o;
}

// tanh-form GELU (one __expf; |err| vs exact ~1e-3, within budget)
__device__ __forceinline__ float gelu_f(float v) {
    float u = v * (0.7978845608f + 0.0356774081f * v * v);
    return v / (1.f + __expf(-2.f * u));
}

__device__ __forceinline__ int pkbf(float a, float b) {
    bf16x2 v; v[0] = (bf16)a; v[1] = (bf16)b;
    return __builtin_bit_cast(int, v);
}

// ---------------- V transpose: vrow [B][T][1024] -> vt [B][1024][T] ----------------
__global__ __launch_bounds__(256) void transpose_v(
    const bf16* __restrict__ vrow, bf16* __restrict__ vt)
{
    __shared__ bf16 tile[64][72];
    const int tb = blockIdx.x;
    const int eb = blockIdx.y;
    const int b  = blockIdx.z;
    const int c  = threadIdx.x;

    const bf16* src = vrow + ((long)b * T_ + tb * 64) * 1024 + eb * 64;
    #pragma unroll
    for (int j = 0; j < 2; j++) {
        int ch = c + j * 256;
        int r = ch >> 3, s = ch & 7;
        *(bf16x8*)&tile[r][s * 8] = *(const bf16x8*)&src[(long)r * 1024 + s * 8];
    }
    __syncthreads();
    bf16* dst = vt + ((long)b * 1024 + eb * 64) * 2048 + tb * 64;
    #pragma unroll
    for (int j = 0; j < 2; j++) {
        int ch = c + j * 256;
        int r = ch >> 3, s = ch & 7;
        bf16x8 o;
        #pragma unroll
        for (int k = 0; k < 8; k++) o[k] = tile[s * 8 + k][r];
        *(bf16x8*)&dst[(long)r * 2048 + s * 8] = o;
    }
}

// ---------------- GEMM: C[M,N] = A[M,K] * Bt[N,K]^T  (round-9 proven structure) ---
// 128x128 tile, ring-2 LDS double-buffer, stage-early, single vmcnt(0)+barrier
// per K-step. BKT=64 (r16-proven): halves per-step sync events; uses both-sides
// seg^=(row&7) XOR swizzle (linear gload_lds dest + pre-swizzled source +
// XOR'd ds_read).
// EPI 1: bf16 out = gelu(acc + bias)
// EPI 2 (SK): split-K over blockIdx.z; f32 atomicAdd into pre-zeroed out;
//   z==0 contributes bias+resid. XCD-region remap on the 8x32 (x,y) grid.
// EPI 3: QKV split: col < 2048 -> qk [M][2048]; col >= 2048 -> vrow [M][1024]
template <int EPI, int SK = 1, int BKT = 32>
__global__ __launch_bounds__(256) void gemm_bt(
    const bf16* __restrict__ A, const bf16* __restrict__ Bt,
    void* __restrict__ outp, void* __restrict__ outp2, const float* __restrict__ bias,
    const float* __restrict__ resid, int M, int N, int K)
{
    __shared__ __align__(16) bf16 As[2][128 * BKT];
    __shared__ __align__(16) bf16 Bs[2][128 * BKT];
    const int tid  = threadIdx.x;
    const int lane = tid & 63;
    const int w    = tid >> 6;
    const int wr   = w >> 1, wc = w & 1;
    const int g    = lane >> 4, cc = lane & 15;

    int bx = blockIdx.x, by = blockIdx.y;
    if constexpr (EPI == 2) {
        // bijective remap on the 8x32 (x,y) grid: L%8 selects XCD
        const int L = blockIdx.y * 8 + blockIdx.x;
        const int xcd = L & 7, grp = L >> 3;          // grp in 0..31
        by = xcd * 4 + (grp >> 3);                    // 4 row-bands per XCD
        bx = grp & 7;
    }
    const int m0 = by * 128, n0 = bx * 128;
    const int NT = (K / SK) / BKT;
    const long koff = (long)blockIdx.z * (K / SK);

    f32x4 acc[4][4] = {};

    // BKT=32 staging pointers (proven path)
    const int c0 = tid, c1 = tid + 256;
    const bf16* gA0 = A  + (long)(m0 + (c0 >> 2)) * K + koff + ((c0 & 3) << 3);
    const bf16* gA1 = A  + (long)(m0 + (c1 >> 2)) * K + koff + ((c1 & 3) << 3);
    const bf16* gB0 = Bt + (long)(n0 + (c0 >> 2)) * K + koff + ((c0 & 3) << 3);
    const bf16* gB1 = Bt + (long)(n0 + (c1 >> 2)) * K + koff + ((c1 & 3) << 3);

    auto stage = [&](int t) {
        const int buf = t & 1;
        if constexpr (BKT == 32) {
            const long k0 = (long)t << 5;
            GLDS(gA0 + k0, &As[buf][c0 * 8]);
            GLDS(gA1 + k0, &As[buf][c1 * 8]);
            GLDS(gB0 + k0, &Bs[buf][c0 * 8]);
            GLDS(gB1 + k0, &Bs[buf][c1 * 8]);
        } else {
            // 1024 chunks of 16B per operand; thread -> 4 chunks each.
            // chunk c -> row c>>3, slot c&7 (linear LDS dest); global seg = slot^(row&7)
            const long k0 = koff + (long)t * BKT;
            #pragma unroll
            for (int j = 0; j < 4; j++) {
                int c = tid + j * 256;
                int r = c >> 3;
                int s = ((c & 7) ^ (r & 7)) << 3;
                GLDS(A  + (long)(m0 + r) * K + k0 + s, &As[buf][c * 8]);
                GLDS(Bt + (long)(n0 + r) * K + k0 + s, &Bs[buf][c * 8]);
            }
        }
    };

    stage(0);
    VMCNT(0);
    __builtin_amdgcn_s_barrier();

    for (int t = 0; t < NT; ++t) {
        const bf16* Ab = As[t & 1];
        const bf16* Bb = Bs[t & 1];
        if (t + 1 < NT) stage(t + 1);

        if constexpr (BKT == 32) {
            bf16x8 af[4], bfr[4];
            #pragma unroll
            for (int mi = 0; mi < 4; mi++)
                af[mi] = *(const bf16x8*)&Ab[(wr * 64 + mi * 16 + cc) * 32 + g * 8];
            #pragma unroll
            for (int ni = 0; ni < 4; ni++)
                bfr[ni] = *(const bf16x8*)&Bb[(wc * 64 + ni * 16 + cc) * 32 + g * 8];
            #pragma unroll
            for (int mi = 0; mi < 4; mi++)
                #pragma unroll
                for (int ni = 0; ni < 4; ni++)
                    acc[mi][ni] = __builtin_amdgcn_mfma_f32_16x16x32_bf16(af[mi], bfr[ni], acc[mi][ni], 0, 0, 0);
        } else {
            const int key = cc & 7;
            bf16x8 af[4][2], bfr[4][2];
            #pragma unroll
            for (int mi = 0; mi < 4; mi++)
                #pragma unroll
                for (int kt = 0; kt < 2; kt++) {
                    int row = wr * 64 + mi * 16 + cc;
                    int sl  = ((kt << 2) | g) ^ key;
                    af[mi][kt] = *(const bf16x8*)&Ab[row * 64 + sl * 8];
                }
            #pragma unroll
            for (int ni = 0; ni < 4; ni++)
                #pragma unroll
                for (int kt = 0; kt < 2; kt++) {
                    int row = wc * 64 + ni * 16 + cc;
                    int sl  = ((kt << 2) | g) ^ key;
                    bfr[ni][kt] = *(const bf16x8*)&Bb[row * 64 + sl * 8];
                }
            #pragma unroll
            for (int kt = 0; kt < 2; kt++)
                #pragma unroll
                for (int mi = 0; mi < 4; mi++)
                    #pragma unroll
                    for (int ni = 0; ni < 4; ni++)
                        acc[mi][ni] = __builtin_amdgcn_mfma_f32_16x16x32_bf16(
                            af[mi][kt], bfr[ni][kt], acc[mi][ni], 0, 0, 0);
        }

        VMCNT(0);
        __builtin_amdgcn_s_barrier();
    }

    #pragma unroll
    for (int mi = 0; mi < 4; mi++) {
        #pragma unroll
        for (int ni = 0; ni < 4; ni++) {
            #pragma unroll
            for (int r = 0; r < 4; r++) {
                int grow = m0 + wr * 64 + mi * 16 + g * 4 + r;
                int gcol = n0 + wc * 64 + ni * 16 + cc;
                float v = acc[mi][ni][r];
                if constexpr (EPI == 3) {
                    if (gcol < 2048)
                        ((bf16*)outp)[(long)grow * 2048 + gcol] = (bf16)v;
                    else
                        ((bf16*)outp2)[(long)grow * 1024 + (gcol - 2048)] = (bf16)v;
                } else if constexpr (EPI == 1) {
                    v += bias[gcol];
                    ((bf16*)outp)[(long)grow * N + gcol] = (bf16)gelu_f(v);
                } else {
                    if (blockIdx.z == 0)
                        v += bias[gcol] + resid[(long)grow * N + gcol];
                    atomicAdd(&((float*)outp)[(long)grow * N + gcol], v);
                }
            }
        }
    }
}

// ---------------- flash attention v5: swapped-QK 32x32 MFMA, in-register softmax ---
// Complementary qt pairing: co-resident blocks (same x,y; b=0/1) get qt = 15-x and x.
__global__ __launch_bounds__(256) void attn_kernel(
    const bf16* __restrict__ qk, const bf16* __restrict__ vt,
    const float* __restrict__ x, bf16* __restrict__ hout)
{
    __shared__ __align__(16) bf16 Ks[2][64 * 64];
    __shared__ __align__(16) bf16 Vs[2][64 * 64];
    const int tid  = threadIdx.x;
    const int lane = tid & 63, w = tid >> 6;
    const int l31 = lane & 31, hi = lane >> 5;
    const int b = blockIdx.z;
    const int qb = b ? blockIdx.x : (gridDim.x - 1 - blockIdx.x);
    const int hh = blockIdx.y;
    const int qbase = qb * 128;
    const int qw0 = qbase + w * 32;
    const int qg  = qw0 + l31;

    const bf16* qkb   = qk + (long)b * T_ * 2048;
    const bf16* kbase = qkb + 1024 + hh * 64;
    const bf16* vbase = vt + ((long)b * 1024 + hh * 64) * 2048;

    bf16x8 qf[4];
    {
        const bf16* qrow = qkb + (long)qg * 2048 + hh * 64;
        #pragma unroll
        for (int ks = 0; ks < 4; ks++) {
            bf16x8 v = *(const bf16x8*)&qrow[ks * 16 + hi * 8];
            #pragma unroll
            for (int j = 0; j < 8; j++) v[j] = (bf16)((float)v[j] * 0.125f);
            qf[ks] = v;
        }
    }

    float m_run = -INFINITY, l_run = 0.f;
    f32x16 o0 = {}, o1 = {};

    const int ntiles = (qbase >> 6) + 2;
    const int my_end = ((qw0 + 31) >> 6) + 1;

    auto stage = [&](int i) {
        const int buf = i & 1;
        const long kv0 = (long)i << 6;
        #pragma unroll
        for (int j = 0; j < 2; j++) {
            int c = tid + j * 256;
            int r = c >> 3, s = c & 7;
            int seg = (s ^ (r & 7)) << 3;
            GLDS(kbase + (kv0 + r) * 2048 + seg, &Ks[buf][c * 8]);
            GLDS(vbase + (long)r * 2048 + kv0 + seg, &Vs[buf][c * 8]);
        }
    };

    stage(0);
    __syncthreads();

    for (int i = 0; i < ntiles; ++i) {
        const int buf = i & 1;
        const int kv0 = i << 6;
        if (i + 1 < ntiles) stage(i + 1);

        if (i < my_end) {
            f32x16 s0 = {}, s1 = {};
            const int xk = l31 & 7;
            #pragma unroll
            for (int ks = 0; ks < 4; ks++) {
                int slot = ((2 * ks + hi) ^ xk) << 3;
                bf16x8 kf0 = *(const bf16x8*)&Ks[buf][l31 * 64 + slot];
                bf16x8 kf1 = *(const bf16x8*)&Ks[buf][(32 + l31) * 64 + slot];
                s0 = __builtin_amdgcn_mfma_f32_32x32x16_bf16(kf0, qf[ks], s0, 0, 0, 0);
                s1 = __builtin_amdgcn_mfma_f32_32x32x16_bf16(kf1, qf[ks], s1, 0, 0, 0);
            }

            if (kv0 + 64 > qw0) {
                #pragma unroll
                for (int r = 0; r < 16; r++) {
                    int kvr = kv0 + (r & 3) + 8 * (r >> 2) + 4 * hi;
                    if (kvr > qg)      s0[r] = -INFINITY;
                    if (kvr + 32 > qg) s1[r] = -INFINITY;
                }
            }

            float pm = s0[0];
            #pragma unroll
            for (int r = 1; r < 16; r++) pm = fmaxf(pm, s0[r]);
            #pragma unroll
            for (int r = 0; r < 16; r++) pm = fmaxf(pm, s1[r]);
            pm = fmaxf(pm, __shfl_xor(pm, 32));

            if (!__all(pm <= m_run + 8.f)) {
                float mn = fmaxf(m_run, pm);
                float al = __expf(m_run - mn);
                m_run = mn;
                l_run *= al;
                #pragma unroll
                for (int r = 0; r < 16; r++) {
                    float av = __shfl(al, (r & 3) + 8 * (r >> 2) + 4 * hi);
                    o0[r] *= av; o1[r] *= av;
                }
            }

            float rs = 0.f;
            #pragma unroll
            for (int r = 0; r < 16; r++) { float p = __expf(s0[r] - m_run); s0[r] = p; rs += p; }
            #pragma unroll
            for (int r = 0; r < 16; r++) { float p = __expf(s1[r] - m_run); s1[r] = p; rs += p; }
            rs += __shfl_xor(rs, 32);
            l_run += rs;

            i32x4 pw[4];
            {
                int d0[4], d1[4];
                #pragma unroll
                for (int m = 0; m < 4; m++) {
                    d0[m] = pkbf(s0[4 * m],     s0[4 * m + 1]);
                    d1[m] = pkbf(s0[4 * m + 2], s0[4 * m + 3]);
                }
                #pragma unroll
                for (int k2 = 0; k2 < 2; k2++) {
                    int r0 = __shfl_xor(d0[2 * k2 + 1 - hi], 32);
                    int r1 = __shfl_xor(d1[2 * k2 + 1 - hi], 32);
                    i32x4 t;
                    t[0] = hi ? r0 : d0[2 * k2];
                    t[1] = hi ? r1 : d1[2 * k2];
                    t[2] = hi ? d0[2 * k2 + 1] : r0;
                    t[3] = hi ? d1[2 * k2 + 1] : r1;
                    pw[k2] = t;
                }
            }
            {
                int d0[4], d1[4];
                #pragma unroll
                for (int m = 0; m < 4; m++) {
                    d0[m] = pkbf(s1[4 * m],     s1[4 * m + 1]);
                    d1[m] = pkbf(s1[4 * m + 2], s1[4 * m + 3]);
                }
                #pragma unroll
                for (int k2 = 0; k2 < 2; k2++) {
                    int r0 = __shfl_xor(d0[2 * k2 + 1 - hi], 32);
                    int r1 = __shfl_xor(d1[2 * k2 + 1 - hi], 32);
                    i32x4 t;
                    t[0] = hi ? r0 : d0[2 * k2];
                    t[1] = hi ? r1 : d1[2 * k2];
                    t[2] = hi ? d0[2 * k2 + 1] : r0;
                    t[3] = hi ? d1[2 * k2 + 1] : r1;
                    pw[2 + k2] = t;
                }
            }

            #pragma unroll
            for (int sl = 0; sl < 4; sl++) {
                bf16x8 pa = __builtin_bit_cast(bf16x8, pw[sl]);
                int slot = ((2 * sl + hi) ^ xk) << 3;
                bf16x8 vf0 = *(const bf16x8*)&Vs[buf][l31 * 64 + slot];
                bf16x8 vf1 = *(const bf16x8*)&Vs[buf][(32 + l31) * 64 + slot];
                o0 = __builtin_amdgcn_mfma_f32_32x32x16_bf16(pa, vf0, o0, 0, 0, 0);
                o1 = __builtin_amdgcn_mfma_f32_32x32x16_bf16(pa, vf1, o1, 0, 0, 0);
            }
        }
        __syncthreads();
    }

    #pragma unroll
    for (int r = 0; r < 16; r++) {
        int qr = (r & 3) + 8 * (r >> 2) + 4 * hi;
        float lr = __shfl(l_run, qr);
        int grow = qbase + w * 32 + qr;
        long base = ((long)b * T_ + grow) * 1024 + hh * 64 + l31;
        hout[base]      = (bf16)(x[base]      + o0[r] / lr);
        hout[base + 32] = (bf16)(x[base + 32] + o1[r] / lr);
    }
}

// ---------------- launch ----------------
extern "C" void kernel_launch(void* const* d_in, const int* in_sizes, int n_in,
                              void* d_out, int out_size, void* d_ws, size_t ws_size,
                              hipStream_t stream) {
    const float* x  = (const float*)d_in[0];
    const float* wq = (const float*)d_in[2];
    const float* wk = (const float*)d_in[3];
    const float* wv = (const float*)d_in[4];
    const float* w1 = (const float*)d_in[5];
    const float* b1 = (const float*)d_in[6];
    const float* w2 = (const float*)d_in[7];
    const float* b2 = (const float*)d_in[8];
    float* out = (float*)d_out;

    char* ws = (char*)d_ws;
    bf16* xb   = (bf16*)(ws);                  // [4096,1024]   8 MB
    bf16* wall = (bf16*)(ws + (8L  << 20));    // [3072,1024]   6 MB
    bf16* w1b  = (bf16*)(ws + (14L << 20));    // [4096,1024]   8 MB
    bf16* w2b  = (bf16*)(ws + (22L << 20));    // [1024,4096]   8 MB
    bf16* qkb  = (bf16*)(ws + (30L << 20));    // [4096,2048]  16 MB
    bf16* vtb  = (bf16*)(ws + (46L << 20));    // [2,1024,2048] 8 MB
    bf16* hbuf = (bf16*)(ws + (54L << 20));    // [4096,1024]   8 MB (also vrow scratch)
    bf16* abuf = (bf16*)(ws + (62L << 20));    // [4096,4096]  32 MB
    bf16* vrow = hbuf;  // consumed by transpose_v BEFORE attn writes hbuf

    // zero out for split-K atomic accumulation (re-zeroed every replay)
    hipMemsetAsync(out, 0, (size_t)BT_ * D_ * sizeof(float), stream);

    // one fused convert dispatch: 15M elems -> 15360 blocks
    cvt_all<<<15360, 256, 0, stream>>>(x, wq, wk, wv, w1, w2, xb, wall, w1b, w2b);

    // QKV projection (BK=64): -> qk [4096,2048] + vrow [4096,1024]
    gemm_bt<3, 1, 64><<<dim3(3 * D_ / 128, BT_ / 128), 256, 0, stream>>>(
        xb, wall, qkb, vrow, nullptr, nullptr, BT_, 3 * D_, D_);

    // V transpose: vrow -> vt [2][1024][2048]
    transpose_v<<<dim3(T_ / 64, D_ / 64, B_), 256, 0, stream>>>(vrow, vtb);

    // attention + residual: hbuf = x + attn_out  (complementary qt pairing)
    attn_kernel<<<dim3(T_ / 128, H_, B_), 256, 0, stream>>>(qkb, vtb, x, hbuf);

    // FFN1 (BK=64): gelu(h @ w1^T + b1) -> abuf [4096,4096] bf16
    gemm_bt<1, 1, 64><<<dim3(DFF_ / 128, BT_ / 128), 256, 0, stream>>>(
        hbuf, w1b, abuf, nullptr, b1, nullptr, BT_, DFF_, D_);

    // FFN2 split-K=2, BK=64 + bias + residual x -> out fp32 [4096,1024] (atomic f32)
    gemm_bt<2, 2, 64><<<dim3(D_ / 128, BT_ / 128, 2), 256, 0, stream>>>(
        abuf, w2b, out, nullptr, b2, x, BT_, D_, DFF_);
}